// Round 11
// baseline (96.823 us; speedup 1.0000x reference)
//
#include <hip/hip_runtime.h>
#include <stdint.h>

// B=8 S=4096 D=768 E=8 R=8; NTOK=32768
// GEMM1: H[NTOK,80] = x @ W1[768,80]   (W1 = [Wd(64) | Wg(8) | pad(8)])
// middle: softmax gate, h2 = (H+bd)@Wm+bm, g2 = [gate*h2 | gate | zeros]  (96 wide, bf16)
// GEMM2: out[NTOK,768] = g2 @ W2[96,768] (W2 rows = [Wu(64) | bu(8) | zeros(24)])
// Pipelined fused: block = 2 x 16-token sub-tiles; sub-tile1 x-loads issued before
// sub-tile0's store phase so HBM reads overlap HBM writes.

typedef short bf16x8 __attribute__((ext_vector_type(8)));
typedef float f32x4 __attribute__((ext_vector_type(4)));

static __device__ __forceinline__ unsigned short f2bf(float f) {
  union { float f; uint32_t u; } v; v.f = f;
  return (unsigned short)((v.u + 0x7fffu + ((v.u >> 16) & 1u)) >> 16);
}

// w1f frags [K0(24)][f(5)][lane(64)][i(8)]: W1[K0*32+(lane>>4)*8+i][f*16+(lane&15)]
// w2f frags [T(48)][K0(3)][lane(64)][i(8)]: W2[K0*32+(lane>>4)*8+i][T*16+(lane&15)]
__global__ void prep_weights(const float* __restrict__ Wd, const float* __restrict__ Wg,
                             const float* __restrict__ Wu, const float* __restrict__ bu,
                             unsigned short* __restrict__ w1f, unsigned short* __restrict__ w2f) {
  int tid = blockIdx.x * 256 + threadIdx.x;
  const int N1 = 24 * 5 * 64 * 8;   // 61440
  if (tid < N1) {
    int i    = tid & 7;
    int lane = (tid >> 3) & 63;
    int fk   = tid >> 9;
    int f = fk % 5, K0 = fk / 5;
    int k = K0 * 32 + (lane >> 4) * 8 + i;
    int j = f * 16 + (lane & 15);
    float val = 0.f;
    if (j < 64)      val = Wd[(size_t)(j >> 3) * 6144 + (size_t)k * 8 + (j & 7)];
    else if (j < 72) val = Wg[(size_t)k * 8 + (j - 64)];
    w1f[tid] = f2bf(val);
  } else {
    int t2 = tid - N1;
    if (t2 >= 48 * 3 * 64 * 8) return;
    int i    = t2 & 7;
    int lane = (t2 >> 3) & 63;
    int tk   = t2 >> 9;
    int K0 = tk % 3, T = tk / 3;
    int k = K0 * 32 + (lane >> 4) * 8 + i;
    int n = T * 16 + (lane & 15);
    float val = 0.f;
    if (k < 64)      val = Wu[(size_t)(k >> 3) * 6144 + (size_t)(k & 7) * 768 + n];
    else if (k < 72) val = bu[(size_t)(k - 64) * 768 + n];
    w2f[t2] = f2bf(val);
  }
}

__global__ __launch_bounds__(256) void moba_pipe(
    const float* __restrict__ x,
    const float* __restrict__ bd, const float* __restrict__ Wm,
    const float* __restrict__ bm, const float* __restrict__ bg,
    const unsigned short* __restrict__ w1f, const unsigned short* __restrict__ w2f,
    float* __restrict__ out) {
  __shared__ float Hs[4][16][84];       // 21504 B (stride 84: bank overlap 2-way max)
  __shared__ unsigned int g2s[16][52];  //  3328 B

  const int tidx = threadIdx.x;
  const int lane = tidx & 63;
  const int wave = tidx >> 6;       // A: K quarter; C: T quarter
  const int arow = lane & 15;
  const int kgrp = lane >> 4;
  const int tok0 = blockIdx.x * 32; // sub-tile s covers [tok0+16s, tok0+16s+16)

  const bf16x8* w1v = (const bf16x8*)w1f + (size_t)(wave * 6) * 320 + lane;
  const bf16x8* w2v = (const bf16x8*)w2f + (size_t)(wave * 12) * 192 + lane;
  const float*  xrow0 = x + (size_t)(tok0 + arow) * 768 + wave * 192 + kgrp * 8;

  float4 xa[12];

  // ---- phase A compute: H(sub-tile) = x @ W1, from xa regs ----
  auto computeA = [&]() {
    f32x4 acc0 = {0,0,0,0}, acc1 = {0,0,0,0}, acc2 = {0,0,0,0}, acc3 = {0,0,0,0}, acc4 = {0,0,0,0};
    #pragma unroll
    for (int i = 0; i < 6; i++) {
      float4 a0 = xa[2 * i];
      float4 a1 = xa[2 * i + 1];
      bf16x8 af;
      af[0] = (short)f2bf(a0.x); af[1] = (short)f2bf(a0.y);
      af[2] = (short)f2bf(a0.z); af[3] = (short)f2bf(a0.w);
      af[4] = (short)f2bf(a1.x); af[5] = (short)f2bf(a1.y);
      af[6] = (short)f2bf(a1.z); af[7] = (short)f2bf(a1.w);
      const bf16x8* bb = w1v + i * 320;
      acc0 = __builtin_amdgcn_mfma_f32_16x16x32_bf16(af, bb[0],   acc0, 0, 0, 0);
      acc1 = __builtin_amdgcn_mfma_f32_16x16x32_bf16(af, bb[64],  acc1, 0, 0, 0);
      acc2 = __builtin_amdgcn_mfma_f32_16x16x32_bf16(af, bb[128], acc2, 0, 0, 0);
      acc3 = __builtin_amdgcn_mfma_f32_16x16x32_bf16(af, bb[192], acc3, 0, 0, 0);
      acc4 = __builtin_amdgcn_mfma_f32_16x16x32_bf16(af, bb[256], acc4, 0, 0, 0);
    }
    int hr = kgrp * 4;               // token = (lane>>4)*4 + reg
    #pragma unroll
    for (int r = 0; r < 4; r++) {
      Hs[wave][hr + r][arow]      = acc0[r];
      Hs[wave][hr + r][16 + arow] = acc1[r];
      Hs[wave][hr + r][32 + arow] = acc2[r];
      Hs[wave][hr + r][48 + arow] = acc3[r];
      Hs[wave][hr + r][64 + arow] = acc4[r];
    }
  };

  // ---- phase B: middle (64 threads, 4 per token) ----
  auto middleB = [&](int s) {
    if (tidx < 64) {
      int t = tidx >> 2;   // token 0..15
      int c = tidx & 3;
      float lg[8];
      float m = -1e30f;
      #pragma unroll
      for (int e = 0; e < 8; e++) {
        lg[e] = Hs[0][t][64 + e] + Hs[1][t][64 + e] + Hs[2][t][64 + e] + Hs[3][t][64 + e] + bg[e];
        m = fmaxf(m, lg[e]);
      }
      float den = 0.f;
      #pragma unroll
      for (int e = 0; e < 8; e++) { lg[e] = __expf(lg[e] - m); den += lg[e]; }
      float inv = 1.f / den;
      unsigned int hv[8];
      #pragma unroll
      for (int ee = 0; ee < 2; ee++) {
        int e = c * 2 + ee;
        float gate = lg[e] * inv;
        float h[8];
        #pragma unroll
        for (int r = 0; r < 8; r++)
          h[r] = Hs[0][t][e * 8 + r] + Hs[1][t][e * 8 + r] + Hs[2][t][e * 8 + r] +
                 Hs[3][t][e * 8 + r] + bd[e * 8 + r];
        #pragma unroll
        for (int q = 0; q < 8; q += 2) {
          float h2a = bm[e * 8 + q], h2b = bm[e * 8 + q + 1];
          #pragma unroll
          for (int r = 0; r < 8; r++) {
            h2a += h[r] * Wm[e * 64 + r * 8 + q];
            h2b += h[r] * Wm[e * 64 + r * 8 + q + 1];
          }
          hv[ee * 4 + (q >> 1)] =
              (unsigned)f2bf(gate * h2a) | ((unsigned)f2bf(gate * h2b) << 16);
        }
      }
      *(uint4*)&g2s[t][8 * c]     = make_uint4(hv[0], hv[1], hv[2], hv[3]);
      *(uint4*)&g2s[t][8 * c + 4] = make_uint4(hv[4], hv[5], hv[6], hv[7]);
      g2s[t][32 + c] = (unsigned)f2bf(lg[c * 2] * inv) | ((unsigned)f2bf(lg[c * 2 + 1] * inv) << 16);
      g2s[t][36 + c * 3 + 0] = 0;
      g2s[t][36 + c * 3 + 1] = 0;
      g2s[t][36 + c * 3 + 2] = 0;
    }
  };

  // ---- phase C: out(sub-tile) = g2s @ W2, swapped operands, f32x4 stores ----
  auto phaseC = [&](int s) {
    bf16x8 a2_0 = *(const bf16x8*)&g2s[arow][kgrp * 4];
    bf16x8 a2_1 = *(const bf16x8*)&g2s[arow][16 + kgrp * 4];
    bf16x8 a2_2 = *(const bf16x8*)&g2s[arow][32 + kgrp * 4];
    float* orow = out + (size_t)(tok0 + s * 16 + arow) * 768 + wave * 192 + kgrp * 4;
    bf16x8 pb[2][3];
    #pragma unroll
    for (int d = 0; d < 2; d++) {
      pb[d][0] = w2v[d * 192];
      pb[d][1] = w2v[d * 192 + 64];
      pb[d][2] = w2v[d * 192 + 128];
    }
    #pragma unroll
    for (int j = 0; j < 12; j++) {
      bf16x8 b0 = pb[j & 1][0], b1 = pb[j & 1][1], b2 = pb[j & 1][2];
      if (j + 2 < 12) {
        pb[j & 1][0] = w2v[(j + 2) * 192];
        pb[j & 1][1] = w2v[(j + 2) * 192 + 64];
        pb[j & 1][2] = w2v[(j + 2) * 192 + 128];
      }
      f32x4 c2 = {0,0,0,0};
      c2 = __builtin_amdgcn_mfma_f32_16x16x32_bf16(b0, a2_0, c2, 0, 0, 0);
      c2 = __builtin_amdgcn_mfma_f32_16x16x32_bf16(b1, a2_1, c2, 0, 0, 0);
      c2 = __builtin_amdgcn_mfma_f32_16x16x32_bf16(b2, a2_2, c2, 0, 0, 0);
      *(f32x4*)(orow + j * 16) = c2;
    }
  };

  // ================= pipeline =================
  // sub-tile 0 loads + compute
  #pragma unroll
  for (int i = 0; i < 6; i++) {
    xa[2 * i]     = *(const float4*)(xrow0 + i * 32);
    xa[2 * i + 1] = *(const float4*)(xrow0 + i * 32 + 4);
  }
  computeA();
  __syncthreads();
  middleB(0);
  __syncthreads();

  // issue sub-tile 1 x-loads, then overlap with sub-tile 0 stores
  {
    const float* xrow1 = xrow0 + (size_t)16 * 768;
    #pragma unroll
    for (int i = 0; i < 6; i++) {
      xa[2 * i]     = *(const float4*)(xrow1 + i * 32);
      xa[2 * i + 1] = *(const float4*)(xrow1 + i * 32 + 4);
    }
  }
  __builtin_amdgcn_sched_barrier(0);   // keep the loads issued above phase C
  phaseC(0);
  computeA();                          // sub-tile 1, consumes xa (loads landed during C0)
  __syncthreads();
  middleB(1);
  __syncthreads();
  phaseC(1);
}

extern "C" void kernel_launch(void* const* d_in, const int* in_sizes, int n_in,
                              void* d_out, int out_size, void* d_ws, size_t ws_size,
                              hipStream_t stream) {
  const float* x  = (const float*)d_in[0];
  const float* Wd = (const float*)d_in[1];
  const float* bd = (const float*)d_in[2];
  const float* Wm = (const float*)d_in[3];
  const float* bm = (const float*)d_in[4];
  const float* Wu = (const float*)d_in[5];
  const float* bu = (const float*)d_in[6];
  const float* Wg = (const float*)d_in[7];
  const float* bg = (const float*)d_in[8];
  unsigned short* w1f = (unsigned short*)d_ws;          // 61440 bf16
  unsigned short* w2f = w1f + 61440;                    // 73728 bf16

  prep_weights<<<528, 256, 0, stream>>>(Wd, Wg, Wu, bu, w1f, w2f);
  moba_pipe<<<1024, 256, 0, stream>>>(x, bd, Wm, bm, bg, w1f, w2f, (float*)d_out);
}

// Round 12
// 75.476 us; speedup vs baseline: 1.2828x; 1.2828x over previous
//
#include <hip/hip_runtime.h>
#include <stdint.h>

// B=8 S=4096 D=768 E=8 R=8; NTOK=32768
// GEMM1: H[NTOK,80] = x @ W1[768,80]   (W1 = [Wd(64) | Wg(8) | pad(8)])
// middle: softmax gate, h2 = (H+bd)@Wm+bm, g2 = [gate*h2 | gate | zeros]  (96 wide, bf16)
// GEMM2: out[NTOK,768] = g2 @ W2[96,768] (W2 rows = [Wu(64) | bu(8) | zeros(24)])
// Coalesced-staged fused: x-tile loaded lane-contiguous -> bf16 LDS (XOR swizzle),
// A-frags via ds_read_b128. 16 tok/block, grid 2048, 3 blocks/CU.

typedef short bf16x8 __attribute__((ext_vector_type(8)));
typedef float f32x4 __attribute__((ext_vector_type(4)));

static __device__ __forceinline__ unsigned short f2bf(float f) {
  union { float f; uint32_t u; } v; v.f = f;
  return (unsigned short)((v.u + 0x7fffu + ((v.u >> 16) & 1u)) >> 16);
}

// w1f frags [K0(24)][f(5)][lane(64)][i(8)]: W1[K0*32+(lane>>4)*8+i][f*16+(lane&15)]
// w2f frags [T(48)][K0(3)][lane(64)][i(8)]: W2[K0*32+(lane>>4)*8+i][T*16+(lane&15)]
__global__ void prep_weights(const float* __restrict__ Wd, const float* __restrict__ Wg,
                             const float* __restrict__ Wu, const float* __restrict__ bu,
                             unsigned short* __restrict__ w1f, unsigned short* __restrict__ w2f) {
  int tid = blockIdx.x * 256 + threadIdx.x;
  const int N1 = 24 * 5 * 64 * 8;   // 61440
  if (tid < N1) {
    int i    = tid & 7;
    int lane = (tid >> 3) & 63;
    int fk   = tid >> 9;
    int f = fk % 5, K0 = fk / 5;
    int k = K0 * 32 + (lane >> 4) * 8 + i;
    int j = f * 16 + (lane & 15);
    float val = 0.f;
    if (j < 64)      val = Wd[(size_t)(j >> 3) * 6144 + (size_t)k * 8 + (j & 7)];
    else if (j < 72) val = Wg[(size_t)k * 8 + (j - 64)];
    w1f[tid] = f2bf(val);
  } else {
    int t2 = tid - N1;
    if (t2 >= 48 * 3 * 64 * 8) return;
    int i    = t2 & 7;
    int lane = (t2 >> 3) & 63;
    int tk   = t2 >> 9;
    int K0 = tk % 3, T = tk / 3;
    int k = K0 * 32 + (lane >> 4) * 8 + i;
    int n = T * 16 + (lane & 15);
    float val = 0.f;
    if (k < 64)      val = Wu[(size_t)(k >> 3) * 6144 + (size_t)(k & 7) * 768 + n];
    else if (k < 72) val = bu[(size_t)(k - 64) * 768 + n];
    w2f[t2] = f2bf(val);
  }
}

__global__ __launch_bounds__(256) void moba_fused(
    const float* __restrict__ x,
    const float* __restrict__ bd, const float* __restrict__ Wm,
    const float* __restrict__ bm, const float* __restrict__ bg,
    const unsigned short* __restrict__ w1f, const unsigned short* __restrict__ w2f,
    float* __restrict__ out) {
  __shared__ unsigned short xs[16 * 768];   // 24576 B, bf16, XOR-swizzled rows
  __shared__ float Hs[4][16][84];           // 21504 B
  __shared__ unsigned int g2s[16][52];      //  3328 B   -> 49408 B total, 3 blocks/CU

  const int tidx = threadIdx.x;
  const int lane = tidx & 63;
  const int wave = tidx >> 6;       // phase A: K quarter; phase C: T quarter
  const int arow = lane & 15;
  const int kgrp = lane >> 4;
  const int tok0 = blockIdx.x * 16;

  // -------- stage: coalesced x loads -> bf16 LDS (swizzled row-major) --------
  // wave owns rows [wave*4, wave*4+4), 3 chunks of 64 float4 per row.
  {
    #pragma unroll
    for (int c = 0; c < 12; c++) {
      int t  = wave * 4 + c / 3;          // c/3 folds at compile time
      int c4 = (c % 3) * 64 + lane;       // float4 index in row (0..191)
      float4 v = *(const float4*)(x + (size_t)(tok0 + t) * 768 + (size_t)c4 * 4);
      uint2 p;
      p.x = (unsigned)f2bf(v.x) | ((unsigned)f2bf(v.y) << 16);
      p.y = (unsigned)f2bf(v.z) | ((unsigned)f2bf(v.w) << 16);
      int byte = (t * 1536 + c4 * 8) ^ ((t & 7) << 4);
      *(uint2*)((char*)xs + byte) = p;
    }
  }
  __syncthreads();

  // -------- Phase A: H = xs @ W1 (4-way K-split, frags via ds_read_b128) --------
  {
    f32x4 acc0 = {0,0,0,0}, acc1 = {0,0,0,0}, acc2 = {0,0,0,0}, acc3 = {0,0,0,0}, acc4 = {0,0,0,0};
    const bf16x8* w1v = (const bf16x8*)w1f + (size_t)(wave * 6) * 320 + lane;

    bf16x8 fb[2][5];
    #pragma unroll
    for (int d = 0; d < 2; d++) {
      #pragma unroll
      for (int q = 0; q < 5; q++) fb[d][q] = w1v[d * 320 + q * 64];
    }
    #pragma unroll
    for (int i = 0; i < 6; i++) {
      int byte = (arow * 1536 + (wave * 192 + i * 32 + kgrp * 8) * 2) ^ ((arow & 7) << 4);
      bf16x8 af = *(const bf16x8*)((char*)xs + byte);
      bf16x8 b0 = fb[i & 1][0], b1 = fb[i & 1][1], b2 = fb[i & 1][2],
             b3 = fb[i & 1][3], b4 = fb[i & 1][4];
      if (i + 2 < 6) {
        #pragma unroll
        for (int q = 0; q < 5; q++) fb[i & 1][q] = w1v[(i + 2) * 320 + q * 64];
      }
      acc0 = __builtin_amdgcn_mfma_f32_16x16x32_bf16(af, b0, acc0, 0, 0, 0);
      acc1 = __builtin_amdgcn_mfma_f32_16x16x32_bf16(af, b1, acc1, 0, 0, 0);
      acc2 = __builtin_amdgcn_mfma_f32_16x16x32_bf16(af, b2, acc2, 0, 0, 0);
      acc3 = __builtin_amdgcn_mfma_f32_16x16x32_bf16(af, b3, acc3, 0, 0, 0);
      acc4 = __builtin_amdgcn_mfma_f32_16x16x32_bf16(af, b4, acc4, 0, 0, 0);
    }
    int hr = kgrp * 4;               // token = (lane>>4)*4 + reg
    #pragma unroll
    for (int r = 0; r < 4; r++) {
      Hs[wave][hr + r][arow]      = acc0[r];
      Hs[wave][hr + r][16 + arow] = acc1[r];
      Hs[wave][hr + r][32 + arow] = acc2[r];
      Hs[wave][hr + r][48 + arow] = acc3[r];
      Hs[wave][hr + r][64 + arow] = acc4[r];
    }
  }
  __syncthreads();

  // -------- Phase B: middle (64 threads, 4 per token) --------
  if (tidx < 64) {
    int t = tidx >> 2;   // token 0..15
    int c = tidx & 3;
    float lg[8];
    float m = -1e30f;
    #pragma unroll
    for (int e = 0; e < 8; e++) {
      lg[e] = Hs[0][t][64 + e] + Hs[1][t][64 + e] + Hs[2][t][64 + e] + Hs[3][t][64 + e] + bg[e];
      m = fmaxf(m, lg[e]);
    }
    float den = 0.f;
    #pragma unroll
    for (int e = 0; e < 8; e++) { lg[e] = __expf(lg[e] - m); den += lg[e]; }
    float inv = 1.f / den;
    unsigned int hv[8];
    #pragma unroll
    for (int ee = 0; ee < 2; ee++) {
      int e = c * 2 + ee;
      float gate = lg[e] * inv;
      float h[8];
      #pragma unroll
      for (int r = 0; r < 8; r++)
        h[r] = Hs[0][t][e * 8 + r] + Hs[1][t][e * 8 + r] + Hs[2][t][e * 8 + r] +
               Hs[3][t][e * 8 + r] + bd[e * 8 + r];
      #pragma unroll
      for (int q = 0; q < 8; q += 2) {
        float h2a = bm[e * 8 + q], h2b = bm[e * 8 + q + 1];
        #pragma unroll
        for (int r = 0; r < 8; r++) {
          h2a += h[r] * Wm[e * 64 + r * 8 + q];
          h2b += h[r] * Wm[e * 64 + r * 8 + q + 1];
        }
        hv[ee * 4 + (q >> 1)] =
            (unsigned)f2bf(gate * h2a) | ((unsigned)f2bf(gate * h2b) << 16);
      }
    }
    *(uint4*)&g2s[t][8 * c]     = make_uint4(hv[0], hv[1], hv[2], hv[3]);
    *(uint4*)&g2s[t][8 * c + 4] = make_uint4(hv[4], hv[5], hv[6], hv[7]);
    g2s[t][32 + c] = (unsigned)f2bf(lg[c * 2] * inv) | ((unsigned)f2bf(lg[c * 2 + 1] * inv) << 16);
    g2s[t][36 + c * 3 + 0] = 0;
    g2s[t][36 + c * 3 + 1] = 0;
    g2s[t][36 + c * 3 + 2] = 0;
  }
  __syncthreads();

  // -------- Phase C: out = g2s @ W2, swapped operands, f32x4 stores --------
  // D = mfma(A=W2frag, B=g2frag): lane holds out[tok0+(lane&15)][T*16+(lane>>4)*4+0..3].
  {
    bf16x8 a2_0 = *(const bf16x8*)&g2s[arow][kgrp * 4];
    bf16x8 a2_1 = *(const bf16x8*)&g2s[arow][16 + kgrp * 4];
    bf16x8 a2_2 = *(const bf16x8*)&g2s[arow][32 + kgrp * 4];

    const bf16x8* w2v = (const bf16x8*)w2f + (size_t)(wave * 12) * 192 + lane;
    float* orow = out + (size_t)(tok0 + arow) * 768 + wave * 192 + kgrp * 4;

    bf16x8 pb[2][3];
    #pragma unroll
    for (int d = 0; d < 2; d++) {
      pb[d][0] = w2v[d * 192];
      pb[d][1] = w2v[d * 192 + 64];
      pb[d][2] = w2v[d * 192 + 128];
    }
    #pragma unroll
    for (int j = 0; j < 12; j++) {
      bf16x8 b0 = pb[j & 1][0], b1 = pb[j & 1][1], b2 = pb[j & 1][2];
      if (j + 2 < 12) {
        pb[j & 1][0] = w2v[(j + 2) * 192];
        pb[j & 1][1] = w2v[(j + 2) * 192 + 64];
        pb[j & 1][2] = w2v[(j + 2) * 192 + 128];
      }
      f32x4 c2 = {0,0,0,0};
      c2 = __builtin_amdgcn_mfma_f32_16x16x32_bf16(b0, a2_0, c2, 0, 0, 0);
      c2 = __builtin_amdgcn_mfma_f32_16x16x32_bf16(b1, a2_1, c2, 0, 0, 0);
      c2 = __builtin_amdgcn_mfma_f32_16x16x32_bf16(b2, a2_2, c2, 0, 0, 0);
      *(f32x4*)(orow + j * 16) = c2;
    }
  }
}

extern "C" void kernel_launch(void* const* d_in, const int* in_sizes, int n_in,
                              void* d_out, int out_size, void* d_ws, size_t ws_size,
                              hipStream_t stream) {
  const float* x  = (const float*)d_in[0];
  const float* Wd = (const float*)d_in[1];
  const float* bd = (const float*)d_in[2];
  const float* Wm = (const float*)d_in[3];
  const float* bm = (const float*)d_in[4];
  const float* Wu = (const float*)d_in[5];
  const float* bu = (const float*)d_in[6];
  const float* Wg = (const float*)d_in[7];
  const float* bg = (const float*)d_in[8];
  unsigned short* w1f = (unsigned short*)d_ws;          // 61440 bf16
  unsigned short* w2f = w1f + 61440;                    // 73728 bf16

  prep_weights<<<528, 256, 0, stream>>>(Wd, Wg, Wu, bu, w1f, w2f);
  moba_fused<<<2048, 256, 0, stream>>>(x, bd, Wm, bm, bg, w1f, w2f, (float*)d_out);
}